// Round 4
// baseline (1802.118 us; speedup 1.0000x reference)
//
#include <hip/hip_runtime.h>

#define BB 64
#define SS 2048
#define HH 128

typedef _Float16 h2_t __attribute__((ext_vector_type(2)));

#if defined(__has_builtin)
#if __has_builtin(__builtin_amdgcn_fdot2)
#define HAVE_FDOT2 1
#endif
#endif

// v_dot2_f32_f16: 2 MACs per VALU instruction.
__device__ __forceinline__ float fdot2f(h2_t a, h2_t b, float c) {
#ifdef HAVE_FDOT2
  return __builtin_amdgcn_fdot2(a, b, c, false);
#else
  return fmaf((float)a[0], (float)b[0], fmaf((float)a[1], (float)b[1], c));
#endif
}

// ---------------------------------------------------------------------------
// GEMM out = in @ W + bias, K=N=128, fully row-parallel.
// R3 post-mortem: the 128x128-tile gemm ran 32 WGs -> 32/256 CUs busy,
// 118us vs ~30us FMA floor. New shape: W register-resident per wave (each
// lane owns 2 output cols x full K = 256 VGPRs of weights), x rows staged
// through per-wave-PRIVATE LDS (no sharing -> ZERO barriers), broadcast
// ds_read (wave-uniform address = free), reg->LDS double buffer.
// 256 WGs x 4 waves = 1024 waves = every CU busy, 128 rows per wave.
// ---------------------------------------------------------------------------
__global__ __launch_bounds__(256) void gemm_bw(const float* __restrict__ in,
                                               const float* __restrict__ W,
                                               const float* __restrict__ bias,
                                               float* __restrict__ out) {
  __shared__ __align__(16) float4 xls[4][2][512];  // per-wave dbuf, 64 KB total
  const int tid = threadIdx.x;
  const int wv = tid >> 6, L = tid & 63;

  float wA[128], wB[128];
  {
    const float2* wp2 = (const float2*)W + L;  // cols (2L, 2L+1)
#pragma unroll
    for (int k = 0; k < 128; ++k) {
      const float2 t = wp2[k * 64];
      wA[k] = t.x;
      wB[k] = t.y;
    }
  }
  const float2 bv = ((const float2*)bias)[L];

  const size_t wave_id = (size_t)blockIdx.x * 4 + wv;
  const size_t base_row = wave_id * 128;
  const float4* gsrc = (const float4*)in;

  float4 r8[8];  // 16-row chunk in flight (8 KB / 64 lanes)
#pragma unroll
  for (int i = 0; i < 8; ++i) r8[i] = gsrc[base_row * 32 + L + 64 * i];

  for (int c = 0; c < 8; ++c) {
    float4* dst = &xls[wv][c & 1][0];
#pragma unroll
    for (int i = 0; i < 8; ++i) dst[L + 64 * i] = r8[i];
    const size_t nrow = (c < 7) ? (base_row + 16 * (c + 1)) : base_row;  // wrap-safe
#pragma unroll
    for (int i = 0; i < 8; ++i) r8[i] = gsrc[nrow * 32 + L + 64 * i];

    const float4* xb4 = &xls[wv][c & 1][0];
    float* orow = out + (base_row + 16 * c) * 128 + 2 * L;
    for (int r = 0; r < 16; ++r) {
      const float4* xr = xb4 + r * 32;
      float a0 = 0, a1 = 0, a2 = 0, a3 = 0, b0 = 0, b1 = 0, b2 = 0, b3 = 0;
#pragma unroll
      for (int k4 = 0; k4 < 32; ++k4) {
        const float4 x4 = xr[k4];  // wave-uniform -> LDS broadcast
        a0 = fmaf(x4.x, wA[4 * k4 + 0], a0);
        a1 = fmaf(x4.y, wA[4 * k4 + 1], a1);
        a2 = fmaf(x4.z, wA[4 * k4 + 2], a2);
        a3 = fmaf(x4.w, wA[4 * k4 + 3], a3);
        b0 = fmaf(x4.x, wB[4 * k4 + 0], b0);
        b1 = fmaf(x4.y, wB[4 * k4 + 1], b1);
        b2 = fmaf(x4.z, wB[4 * k4 + 2], b2);
        b3 = fmaf(x4.w, wB[4 * k4 + 3], b3);
      }
      float2 o;
      o.x = (a0 + a1) + (a2 + a3) + bv.x;
      o.y = (b0 + b1) + (b2 + b3) + bv.y;
      *(float2*)(orow + (size_t)r * 128) = o;  // lanes consecutive -> coalesced
    }
  }
}

// ---------------------------------------------------------------------------
// Recurrence: h_t = relu(tanh(xi_t + h_{t-1} @ Wh)). ONE WAVE per batch row.
// R1-R3 showed ~1000 cyc/step invariant under LDS-traffic and FMA changes ->
// the multi-wave write->s_barrier->read->shfl serial chain was the floor.
// Here: no barrier (single wave, in-order DS pipe), no shuffles (each lane
// owns 2 full-K output columns), h exchanged via a 512 B LDS buffer read
// with wave-uniform addresses (broadcast). K-dots use v_dot2_f32_f16 with
// fp16 weights/h: 128 instrs/lane/step instead of 256 fp32 FMAs.
// ---------------------------------------------------------------------------
__global__ __launch_bounds__(64) void rnn_rec(float* __restrict__ xi,
                                              const float* __restrict__ Wh) {
  __shared__ __align__(16) h2_t hls[2][64];
  const int L = threadIdx.x;

  // wA/wB[k2] = fp16 pair (Wh[2k2][j], Wh[2k2+1][j]) for j = 2L, 2L+1.
  h2_t wA[64], wB[64];
  {
    const float2* wp2 = (const float2*)Wh + L;
#pragma unroll
    for (int k2 = 0; k2 < 64; ++k2) {
      const float2 w0 = wp2[(2 * k2) * 64];
      const float2 w1 = wp2[(2 * k2 + 1) * 64];
      wA[k2] = h2_t{(_Float16)w0.x, (_Float16)w1.x};
      wB[k2] = h2_t{(_Float16)w0.y, (_Float16)w1.y};
    }
  }

  hls[0][L] = h2_t{(_Float16)0.f, (_Float16)0.f};  // h0 = 0

  float* xb = xi + (size_t)blockIdx.x * (SS * HH) + 2 * L;
  constexpr int PF = 8;  // xi prefetch depth (consumed ~8 steps later)
  float2 pre[PF];
#pragma unroll
  for (int p = 0; p < PF; ++p) pre[p] = *(const float2*)(xb + p * HH);

  for (int t0 = 0; t0 < SS; t0 += PF) {
#pragma unroll
    for (int p = 0; p < PF; ++p) {
      const int t = t0 + p;
      // bulk-load h (128 fp16 = 256 B) with 16 wave-uniform b128 reads
      int4 raw[16];
      const int4* hp = (const int4*)(&hls[t & 1][0]);
#pragma unroll
      for (int i = 0; i < 16; ++i) raw[i] = hp[i];
      const h2_t* h2 = (const h2_t*)raw;
      float aA[4] = {0.f, 0.f, 0.f, 0.f}, aB[4] = {0.f, 0.f, 0.f, 0.f};
#pragma unroll
      for (int k2 = 0; k2 < 64; ++k2) {
        aA[k2 & 3] = fdot2f(h2[k2], wA[k2], aA[k2 & 3]);
        aB[k2 & 3] = fdot2f(h2[k2], wB[k2], aB[k2 & 3]);
      }
      const float vx = pre[p].x + ((aA[0] + aA[1]) + (aA[2] + aA[3]));
      const float vy = pre[p].y + ((aB[0] + aB[1]) + (aB[2] + aB[3]));
      // tanh(v) = 1 - 2/(exp2(2v*log2e)+1); safe at +-inf
      const float ex = __builtin_amdgcn_exp2f(vx * 2.8853900817779268f);
      const float ey = __builtin_amdgcn_exp2f(vy * 2.8853900817779268f);
      const float hx = fmaxf(1.f - 2.f * __builtin_amdgcn_rcpf(ex + 1.f), 0.f);
      const float hy = fmaxf(1.f - 2.f * __builtin_amdgcn_rcpf(ey + 1.f), 0.f);
      hls[(t & 1) ^ 1][L] = h2_t{(_Float16)hx, (_Float16)hy};  // h for t+1
      float2 st;
      st.x = hx;
      st.y = hy;
      *(float2*)(xb + (size_t)t * HH) = st;  // hs for phase 3 (fire-and-forget)
      const int tn = t + PF;
      if (tn < SS) pre[p] = *(const float2*)(xb + (size_t)tn * HH);
    }
  }
}

extern "C" void kernel_launch(void* const* d_in, const int* in_sizes, int n_in,
                              void* d_out, int out_size, void* d_ws, size_t ws_size,
                              hipStream_t stream) {
  const float* x  = (const float*)d_in[0];
  const float* Wi = (const float*)d_in[1];
  const float* Wh = (const float*)d_in[2];
  const float* b  = (const float*)d_in[3];
  const float* Wo = (const float*)d_in[4];
  const float* bo = (const float*)d_in[5];
  float* y  = (float*)d_out;
  float* xi = (float*)d_ws;  // 64 MB: holds xi, then overwritten in-place with hs

  gemm_bw<<<256, 256, 0, stream>>>(x, Wi, b, xi);
  rnn_rec<<<BB, 64, 0, stream>>>(xi, Wh);
  gemm_bw<<<256, 256, 0, stream>>>(xi, Wo, bo, y);
}

// Round 5
// 1318.196 us; speedup vs baseline: 1.3671x; 1.3671x over previous
//
#include <hip/hip_runtime.h>

#define BB 64
#define SS 2048
#define HH 128

typedef _Float16 h2_t __attribute__((ext_vector_type(2)));

#if defined(__has_builtin)
#if __has_builtin(__builtin_amdgcn_fdot2)
#define HAVE_FDOT2 1
#endif
#endif

// v_dot2_f32_f16: 2 MACs per VALU instruction.
__device__ __forceinline__ float fdot2f(h2_t a, h2_t b, float c) {
#ifdef HAVE_FDOT2
  return __builtin_amdgcn_fdot2(a, b, c, false);
#else
  return fmaf((float)a[0], (float)b[0], fmaf((float)a[1], (float)b[1], c));
#endif
}

// ---------------------------------------------------------------------------
// GEMM: out[r][j] = in[r][:] @ W[:][j] + bias[j], K=N=128. 128x128 tile/WG,
// 1024 WGs, thread = 8 rows x 8 cols. (R3-measured ~118us per call; R4's
// register-resident-W variant spilled to scratch at ~480us -- reverted.)
// ---------------------------------------------------------------------------
__global__ __launch_bounds__(256) void gemm128v2(const float* __restrict__ in,
                                                 const float* __restrict__ W,
                                                 const float* __restrict__ bias,
                                                 float* __restrict__ out) {
  __shared__ __align__(16) float xls[128 * 128];   // 64 KB
  __shared__ __align__(16) float wls[128 * 140];   // 70 KB (padded rows)
  const int t = threadIdx.x;
  const long row0 = (long)blockIdx.x * 128;

  {
    const float4* g4 = (const float4*)(in + row0 * 128);
    float4* l4 = (float4*)xls;
#pragma unroll
    for (int it = 0; it < 16; ++it) l4[t + 256 * it] = g4[t + 256 * it];
  }
  {
#pragma unroll
    for (int it = 0; it < 16; ++it) {
      const int fidx = (t + 256 * it) * 4;
      const int k = fidx >> 7, j = fidx & 127;
      const float4 v = *(const float4*)(W + fidx);
      *(float4*)(wls + k * 140 + j + 4 * (j >> 5)) = v;
    }
  }
  __syncthreads();

  const int rg = t >> 4, cg = t & 15;
  const float* xrow = xls + (rg * 8) * 128;
  const float* wcol = wls + cg * 8 + 4 * (cg >> 2);

  float4 acc0[8], acc1[8];
#pragma unroll
  for (int r = 0; r < 8; ++r) {
    acc0[r] = make_float4(0.f, 0.f, 0.f, 0.f);
    acc1[r] = make_float4(0.f, 0.f, 0.f, 0.f);
  }

  for (int k = 0; k < 128; k += 4) {
    float4 xv[8];
#pragma unroll
    for (int r = 0; r < 8; ++r) xv[r] = *(const float4*)(xrow + r * 128 + k);
#pragma unroll
    for (int kk = 0; kk < 4; ++kk) {
      const float* wr = wcol + (k + kk) * 140;
      const float4 w0 = *(const float4*)(wr);
      const float4 w1 = *(const float4*)(wr + 4);
#pragma unroll
      for (int r = 0; r < 8; ++r) {
        const float xs = (kk == 0) ? xv[r].x : (kk == 1) ? xv[r].y
                       : (kk == 2) ? xv[r].z : xv[r].w;
        acc0[r].x = fmaf(xs, w0.x, acc0[r].x);
        acc0[r].y = fmaf(xs, w0.y, acc0[r].y);
        acc0[r].z = fmaf(xs, w0.z, acc0[r].z);
        acc0[r].w = fmaf(xs, w0.w, acc0[r].w);
        acc1[r].x = fmaf(xs, w1.x, acc1[r].x);
        acc1[r].y = fmaf(xs, w1.y, acc1[r].y);
        acc1[r].z = fmaf(xs, w1.z, acc1[r].z);
        acc1[r].w = fmaf(xs, w1.w, acc1[r].w);
      }
    }
  }

  const float4 b0 = *(const float4*)(bias + cg * 8);
  const float4 b1 = *(const float4*)(bias + cg * 8 + 4);
  float* op = out + (row0 + rg * 8) * 128 + cg * 8;
#pragma unroll
  for (int r = 0; r < 8; ++r) {
    float4 o0, o1;
    o0.x = acc0[r].x + b0.x; o0.y = acc0[r].y + b0.y;
    o0.z = acc0[r].z + b0.z; o0.w = acc0[r].w + b0.w;
    o1.x = acc1[r].x + b1.x; o1.y = acc1[r].y + b1.y;
    o1.z = acc1[r].z + b1.z; o1.w = acc1[r].w + b1.w;
    *(float4*)(op + r * 128) = o0;
    *(float4*)(op + r * 128 + 4) = o1;
  }
}

// ---------------------------------------------------------------------------
// Recurrence: h_t = relu(tanh(xi_t + h_{t-1} @ Wh)). ONE WAVE per batch row,
// no barriers, no shuffles; h via 512 B LDS double buffer; fp16 v_dot2.
//
// R4 post-mortem: ~1000 cyc/step was INVARIANT across barrier/LDS/shfl
// restructurings (R1-R4). Common factor: the per-step prefetch was
// PREDICATED (`if (tn < SS) load`), which breaks precise vmcnt tracking at
// the branch merge -> conservative near-vmcnt(0) wait every step -> a fresh
// ~900-cyc global-load latency on the serial path. Fix: UNCONDITIONAL
// wrapped prefetch (tn = (t+PF) & (SS-1)); tail wrap-loads hit rows already
// overwritten with h, but those pre[] values are never consumed -> safe.
// Straight-line body -> vmcnt(15) targeting the 8-step-old load.
// ---------------------------------------------------------------------------
__global__ __launch_bounds__(64) void rnn_rec(float* __restrict__ xi,
                                              const float* __restrict__ Wh) {
  __shared__ __align__(16) h2_t hls[2][64];
  const int L = threadIdx.x;

  // wA/wB[k2] = fp16 pair (Wh[2k2][j], Wh[2k2+1][j]) for j = 2L, 2L+1.
  h2_t wA[64], wB[64];
  {
    const float2* wp2 = (const float2*)Wh + L;
#pragma unroll
    for (int k2 = 0; k2 < 64; ++k2) {
      const float2 w0 = wp2[(2 * k2) * 64];
      const float2 w1 = wp2[(2 * k2 + 1) * 64];
      wA[k2] = h2_t{(_Float16)w0.x, (_Float16)w1.x};
      wB[k2] = h2_t{(_Float16)w0.y, (_Float16)w1.y};
    }
  }

  hls[0][L] = h2_t{(_Float16)0.f, (_Float16)0.f};  // h0 = 0

  float* xb = xi + (size_t)blockIdx.x * (SS * HH) + 2 * L;
  constexpr int PF = 8;  // consumed 8 steps (~3500 cyc) after issue
  float2 pre[PF];
#pragma unroll
  for (int p = 0; p < PF; ++p) pre[p] = *(const float2*)(xb + p * HH);

  for (int t0 = 0; t0 < SS; t0 += PF) {
#pragma unroll
    for (int p = 0; p < PF; ++p) {
      const int t = t0 + p;
      // bulk-load h (128 fp16 = 256 B) with 16 wave-uniform b128 reads
      int4 raw[16];
      const int4* hp = (const int4*)(&hls[t & 1][0]);
#pragma unroll
      for (int i = 0; i < 16; ++i) raw[i] = hp[i];
      const h2_t* h2 = (const h2_t*)raw;
      float aA[4] = {0.f, 0.f, 0.f, 0.f}, aB[4] = {0.f, 0.f, 0.f, 0.f};
#pragma unroll
      for (int k2 = 0; k2 < 64; ++k2) {
        aA[k2 & 3] = fdot2f(h2[k2], wA[k2], aA[k2 & 3]);
        aB[k2 & 3] = fdot2f(h2[k2], wB[k2], aB[k2 & 3]);
      }
      const float vx = pre[p].x + ((aA[0] + aA[1]) + (aA[2] + aA[3]));
      const float vy = pre[p].y + ((aB[0] + aB[1]) + (aB[2] + aB[3]));
      // tanh(v) = 1 - 2/(exp2(2v*log2e)+1); safe at +-inf
      const float ex = __builtin_amdgcn_exp2f(vx * 2.8853900817779268f);
      const float ey = __builtin_amdgcn_exp2f(vy * 2.8853900817779268f);
      const float hx = fmaxf(1.f - 2.f * __builtin_amdgcn_rcpf(ex + 1.f), 0.f);
      const float hy = fmaxf(1.f - 2.f * __builtin_amdgcn_rcpf(ey + 1.f), 0.f);
      hls[(t & 1) ^ 1][L] = h2_t{(_Float16)hx, (_Float16)hy};  // h for t+1
      float2 st;
      st.x = hx;
      st.y = hy;
      *(float2*)(xb + (size_t)t * HH) = st;  // hs for phase 3 (fire-and-forget)
      // UNCONDITIONAL wrapped prefetch: keeps the body branch-free so the
      // waitcnt pass emits a precise vmcnt for the 8-step-old load.
      const int tn = (t + PF) & (SS - 1);
      pre[p] = *(const float2*)(xb + (size_t)tn * HH);
    }
  }
}

extern "C" void kernel_launch(void* const* d_in, const int* in_sizes, int n_in,
                              void* d_out, int out_size, void* d_ws, size_t ws_size,
                              hipStream_t stream) {
  const float* x  = (const float*)d_in[0];
  const float* Wi = (const float*)d_in[1];
  const float* Wh = (const float*)d_in[2];
  const float* b  = (const float*)d_in[3];
  const float* Wo = (const float*)d_in[4];
  const float* bo = (const float*)d_in[5];
  float* y  = (float*)d_out;
  float* xi = (float*)d_ws;  // 64 MB: holds xi, then overwritten in-place with hs

  gemm128v2<<<(BB * SS) / 128, 256, 0, stream>>>(x, Wi, b, xi);
  rnn_rec<<<BB, 64, 0, stream>>>(xi, Wh);
  gemm128v2<<<(BB * SS) / 128, 256, 0, stream>>>(xi, Wo, bo, y);
}